// Round 4
// baseline (157.824 us; speedup 1.0000x reference)
//
#include <hip/hip_runtime.h>
#include <hip/hip_bf16.h>
#include <math.h>

#define SUMS 199
#define NBLK 2048   // 8 images = 2 batch elements per block, 256 threads

typedef __attribute__((ext_vector_type(8))) short short8;   // 8 bf16
typedef __attribute__((ext_vector_type(4))) float float4v;  // MFMA acc

union Frag8 { short8 v; unsigned u[4]; uint4 q; };

static __device__ inline unsigned pk_bf16(float a, float b) {
    __hip_bfloat162 h = __float22bfloat162_rn(make_float2(a, b));
    union { __hip_bfloat162 h; unsigned u; } c; c.h = h; return c.u;
}

// ---- pre-kernel: all weight fragments -> d_ws (bf16 frag layout) ----
// c2 K-map (dense): pos = 4*s + h, ky = pos/5, kx = pos%5, valid pos < 25
// => conv2 needs only 7 K-steps (K=224) instead of 8 (K=256).
__global__ __launch_bounds__(256) void convert_weights(
    const float* __restrict__ f1w, const float* __restrict__ f2w,
    const float* __restrict__ f3w, const float* __restrict__ c1w,
    const float* __restrict__ c2w, uint4* __restrict__ ws)
{
    const int g = blockIdx.x * 256 + threadIdx.x;
    if (g >= 6400) return;
    float v[8];
    if (g < 5824) {
        const float* W; int O, K, ld, nt, s, l;
        if (g < 4096)      { W = f1w; O = 120; K = 256; ld = 256; nt = g >> 9; s = (g >> 6) & 7; l = g & 63; }
        else if (g < 5632) { const int f = g - 4096; W = f2w; O = 84; K = 120; ld = 120; nt = f >> 8; s = (f >> 6) & 3; l = f & 63; }
        else               { const int f = g - 5632; W = f3w; O = 10; K = 84;  ld = 84;  nt = 0; s = f >> 6; l = f & 63; }
        const int o = nt * 16 + (l & 15);
        #pragma unroll
        for (int j = 0; j < 8; ++j) {
            const int k = 32 * s + 8 * (l >> 4) + j;
            v[j] = (o < O && k < K) ? W[o * ld + k] : 0.f;
        }
    } else if (g < 6336) {
        const int f = g - 5824, s = f >> 6, l = f & 63;
        const int c = l & 15, h = l >> 4;
        const int pos = 4 * s + h;           // dense position index
        const int ky = pos / 5, kx = pos % 5;
        const bool ok = (pos < 25);
        #pragma unroll
        for (int jp = 0; jp < 4; ++jp) {
            v[2 * jp]     = (ok && 2 * jp < 6)     ? c2w[c * 150 + (2 * jp) * 25 + ky * 5 + kx]     : 0.f;
            v[2 * jp + 1] = (ok && 2 * jp + 1 < 6) ? c2w[c * 150 + (2 * jp + 1) * 25 + ky * 5 + kx] : 0.f;
        }
    } else {
        const int l = (g - 6336) & 63;
        const int c = l & 15, h = l >> 4;
        const int oc = c >> 1, xs = c & 1;
        #pragma unroll
        for (int j = 0; j < 8; ++j) {
            const int p = h * 4 + (j >> 1);
            float w = 0.f;
            if (p < 15 && c < 12) {
                const int ky = p / 3, kx = 2 * (p % 3) + (j & 1) - xs;
                if (kx >= 0 && kx < 5) w = c1w[oc * 25 + ky * 5 + kx];
            }
            v[j] = w;
        }
    }
    uint4 r;
    r.x = pk_bf16(v[0], v[1]); r.y = pk_bf16(v[2], v[3]);
    r.z = pk_bf16(v[4], v[5]); r.w = pk_bf16(v[6], v[7]);
    ws[g] = r;
}

// LDS map, 19840 B -> 8 blocks/CU (32 waves/CU, was 4 blocks/16 waves):
//  [0,6336)       imgu bf16 [4 wave-slots][396 dw] (1 image/slot/pass).
//                 After convs: A2 [8][68dw]@0, A3 [8][52dw]@2560,
//                 pgf [8][12]f32 @4352, Hf/Lf [2][20]f32 @4736/@4896.
//  [6336,15616)   p1 bf16 [4 wave-slots][145 uint4], ch-6/7 dwords stay 0.
//  [15616,19840)  A1 bf16 [8 img][132 dw]
//
// Front is fully wave-private: wave w stages image (pass*4+w), runs conv1
// (N-cols = (qyo,par,qxo): one image fills 16 cols; pool-y via shfl^4;
// stores hit banks 16qyo+4qxo+h, all distinct -> conflict-free), then conv2
// from its own p1 slot. No barriers until A1 is complete.
// fc1/fc2/fc3 duplicate image rows via (c&7) so all LDS reads stay in the
// 8-row regions (garbage rows are MFMA-row-isolated, outputs discarded).
// Circuit factorization (exact regroup): n1+n2 = 10(h1+h2)+(l1+l2) =>
// P_sum = (ptens1 (*) ptens2) outer-convolved with (pones1 (*) pones2);
// H,L are 19-long convs; each of the 199 outputs needs <=2 H[b]*L[a] terms.
// Tail runs on waves 0,1 (one batch element each), barrier-free.
__global__ __launch_bounds__(256, 8) void lenet_circuit_kernel(
    const float* __restrict__ images,
    const float* __restrict__ c1b, const float* __restrict__ c2b,
    const float* __restrict__ f1b, const float* __restrict__ f2b,
    const float* __restrict__ f3b, const uint4* __restrict__ wsb,
    float* __restrict__ out)
{
    __shared__ __align__(16) unsigned char s_mem[19840];
    unsigned*       imgu = (unsigned*)s_mem;
    uint2*          imgw = (uint2*)s_mem;
    unsigned short* p1s  = (unsigned short*)(s_mem + 6336);
    const uint4*    p1u4 = (const uint4*)(s_mem + 6336);
    unsigned*       A1d  = (unsigned*)(s_mem + 15616);
    const uint4*    A1q  = (const uint4*)(s_mem + 15616);
    float*          pgf  = (float*)(s_mem + 4352);    // [8][12] probs
    float*          Hf   = (float*)(s_mem + 4736);    // [2][20]
    float*          Lf   = (float*)(s_mem + 4896);    // [2][20]

    const int t = threadIdx.x, bid = blockIdx.x;
    const int lane = t & 63, wav = t >> 6;   // 4 waves
    const int c = lane & 15, h = lane >> 4;
    const uint4 z4 = {0u, 0u, 0u, 0u};

    // conv1 column decomposition: c = (qyo<<3) | (par<<2) | qxo
    const int qxo = c & 3, par = (c >> 2) & 1, qyo = c >> 3;

    // ---- zero own p1 slot (wave-private; pad ch 6-7 must stay 0) ----
    {
        uint4* pz = (uint4*)(s_mem + 6336) + wav * 145;
        for (int j = lane; j < 145; j += 64) pz[j] = z4;
    }
    // ---- load weight fragments (coalesced) ----
    Frag8 a1; a1.q = wsb[6336 + lane];
    int koff[7];
    #pragma unroll
    for (int s = 0; s < 7; ++s) {
        const int pos = 4 * s + h;
        koff[s] = (pos < 25) ? (pos / 5) * 12 + (pos % 5) : 0;
    }
    int pd[4];
    #pragma unroll
    for (int q = 0; q < 4; ++q) {
        const int p = 4 * h + q;
        pd[q] = (p < 15) ? (p / 3) * 14 + (p % 3) : 0;
    }
    float bias0 = 0.f, bias1 = 0.f;
    if (h < 3) { bias0 = c1b[2 * h]; bias1 = c1b[2 * h + 1]; }
    const float b2v = c2b[c];

    // ================= two passes, fully wave-private =================
    for (int pass = 0; pass < 2; ++pass) {
        // ---- stage own image fp32 -> bf16 into own imgu slot ----
        {
            const float4* g = (const float4*)(images) +
                              ((size_t)bid * 8 + pass * 4 + wav) * 196;
            #pragma unroll
            for (int k = 0; k < 4; ++k) {
                const int i = lane + 64 * k;
                if (i < 196) {
                    const float4 v = g[i];
                    uint2 wv; wv.x = pk_bf16(v.x, v.y); wv.y = pk_bf16(v.z, v.w);
                    imgw[wav * 198 + i] = wv;
                }
            }
        }
        // ---- conv1: 18 MFMA over own image ----
        {
            const int sbase = wav * 396 + (2 * qyo + par) * 14 + qxo;
            for (int Q = 0; Q < 6; ++Q) {
                #pragma unroll
                for (int qxg = 0; qxg < 3; ++qxg) {
                    const int base = sbase + Q * 56 + qxg * 4;
                    Frag8 bf;
                    #pragma unroll
                    for (int q = 0; q < 4; ++q) bf.u[q] = imgu[base + pd[q]];
                    float4v acc = {0.f, 0.f, 0.f, 0.f};
                    acc = __builtin_amdgcn_mfma_f32_16x16x32_bf16(a1.v, bf.v, acc, 0, 0, 0);
                    float v0 = fmaxf(acc[0], acc[1]);   // ch 2h, xs-pooled
                    float v1 = fmaxf(acc[2], acc[3]);   // ch 2h+1
                    v0 = fmaxf(v0, __shfl_xor(v0, 4));  // y-parity pool: lane bit 2
                    v1 = fmaxf(v1, __shfl_xor(v1, 4));
                    if (par == 0 && h < 3) {
                        const int qy = 2 * Q + qyo, qx = qxg * 4 + qxo;
                        *(unsigned*)&p1s[wav * 1160 + qy * 96 + qx * 8 + 2 * h] =
                            pk_bf16(fmaxf(v0 + bias0, 0.f), fmaxf(v1 + bias1, 0.f));
                    }
                }
            }
        }
        // ---- conv2: 28 MFMA over own p1 slot; writes A1 row (pass*4+wav) ----
        {
            const int pxl = (c & 1) + 2 * ((c >> 2) & 1);
            const int pyl = ((c >> 1) & 1) + 2 * ((c >> 3) & 1);
            int pbase[4];
            #pragma unroll
            for (int mt = 0; mt < 4; ++mt)
                pbase[mt] = wav * 145 + (pyl + 4 * (mt >> 1)) * 12 + pxl + 4 * (mt & 1);
            float4v acc[4];
            #pragma unroll
            for (int mt = 0; mt < 4; ++mt) acc[mt] = (float4v){0.f, 0.f, 0.f, 0.f};
            #pragma unroll
            for (int s = 0; s < 7; ++s) {
                Frag8 wz; wz.q = wsb[5824 + s * 64 + lane];  // L1/L2-hot stream
                #pragma unroll
                for (int mt = 0; mt < 4; ++mt) {
                    Frag8 af; af.q = p1u4[pbase[mt] + koff[s]];
                    acc[mt] = __builtin_amdgcn_mfma_f32_16x16x32_bf16(af.v, wz.v, acc[mt], 0, 0, 0);
                }
            }
            const int img = pass * 4 + wav;
            #pragma unroll
            for (int mt = 0; mt < 4; ++mt) {
                const float p = fmaxf(fmaxf(acc[mt][0], acc[mt][1]),
                                      fmaxf(acc[mt][2], acc[mt][3]));
                float v = fmaxf(p + b2v, 0.f);
                const float vp = __shfl_xor(v, 16);
                if ((h & 1) == 0) {
                    const int qy = (h >> 1) + 2 * (mt >> 1);
                    A1d[img * 132 + c * 8 + qy * 2 + (mt & 1)] = pk_bf16(v, vp);
                }
            }
        }
    }
    __syncthreads();     // A1 complete (8 images); imgu/p1 dead

    // ---- fc1 via MFMA (2 n-tiles/wave, 16 MFMA); image rows via (c&7) ----
    {
        unsigned* A2d = (unsigned*)s_mem;
        if (t < 32) A2d[(t >> 2) * 68 + 60 + (t & 3)] = 0u;   // k-pad 120-127
        float4v acc0 = {0.f, 0.f, 0.f, 0.f}, acc1 = acc0;
        const int nt0 = 2 * wav;
        #pragma unroll
        for (int s = 0; s < 8; ++s) {
            Frag8 af; af.q = A1q[(c & 7) * 33 + 4 * s + h];
            Frag8 b0; b0.q = wsb[(nt0 * 8 + s) * 64 + lane];
            Frag8 b1; b1.q = wsb[((nt0 + 1) * 8 + s) * 64 + lane];
            acc0 = __builtin_amdgcn_mfma_f32_16x16x32_bf16(af.v, b0.v, acc0, 0, 0, 0);
            acc1 = __builtin_amdgcn_mfma_f32_16x16x32_bf16(af.v, b1.v, acc1, 0, 0, 0);
        }
        #pragma unroll
        for (int ntl = 0; ntl < 2; ++ntl) {
            const int o = 32 * wav + 16 * ntl + c;
            const float bias = (o < 120) ? f1b[o] : 0.f;
            #pragma unroll
            for (int r = 0; r < 4; ++r) {
                float v = fmaxf((ntl ? acc1[r] : acc0[r]) + bias, 0.f);
                const float vp = __shfl_xor(v, 1);
                if ((c & 1) == 0 && o < 120 && h < 2)
                    A2d[(4 * h + r) * 68 + (o >> 1)] = pk_bf16(v, vp);
            }
        }
    }
    __syncthreads();

    // ---- fc2 via MFMA (waves 0-2, 2 n-tiles each) ----
    {
        unsigned* A3d = (unsigned*)(s_mem + 2560);
        if (t < 48) A3d[(t / 6) * 52 + 42 + (t % 6)] = 0u;    // k-pad 84-95
        if (wav < 3) {
            const uint4* A2q = (const uint4*)s_mem;
            float4v acc0 = {0.f, 0.f, 0.f, 0.f}, acc1 = acc0;
            const int nt0 = 2 * wav;
            #pragma unroll
            for (int s = 0; s < 4; ++s) {
                Frag8 af; af.q = A2q[(c & 7) * 17 + 4 * s + h];
                Frag8 b0; b0.q = wsb[4096 + (nt0 * 4 + s) * 64 + lane];
                Frag8 b1; b1.q = wsb[4096 + ((nt0 + 1) * 4 + s) * 64 + lane];
                acc0 = __builtin_amdgcn_mfma_f32_16x16x32_bf16(af.v, b0.v, acc0, 0, 0, 0);
                acc1 = __builtin_amdgcn_mfma_f32_16x16x32_bf16(af.v, b1.v, acc1, 0, 0, 0);
            }
            #pragma unroll
            for (int ntl = 0; ntl < 2; ++ntl) {
                const int o = 32 * wav + 16 * ntl + c;
                const float bias = (o < 84) ? f2b[o] : 0.f;
                #pragma unroll
                for (int r = 0; r < 4; ++r) {
                    float v = fmaxf((ntl ? acc1[r] : acc0[r]) + bias, 0.f);
                    const float vp = __shfl_xor(v, 1);
                    if ((c & 1) == 0 && o < 84 && h < 2)
                        A3d[(4 * h + r) * 52 + (o >> 1)] = pk_bf16(v, vp);
                }
            }
        }
    }
    __syncthreads();

    // ==== per-wave tail: waves 0,1 each own one batch element (be = wav).
    // fc3 rows m = 4h+r: wave w keeps h == w (its be's 4 digit images).
    // All LDS writes row-disjoint across the 2 waves; no barriers.
    if (wav < 2) {
        const uint4* A3q = (const uint4*)(s_mem + 2560);
        float4v acc = {0.f, 0.f, 0.f, 0.f};
        #pragma unroll
        for (int s = 0; s < 3; ++s) {
            Frag8 af; af.q = A3q[(c & 7) * 13 + 4 * s + h];
            Frag8 b; b.q = wsb[5632 + s * 64 + lane];
            acc = __builtin_amdgcn_mfma_f32_16x16x32_bf16(af.v, b.v, acc, 0, 0, 0);
        }
        const float bias = (c < 10) ? f3b[c] : 0.f;
        float x[4], m[4], e[4], sm[4];
        #pragma unroll
        for (int r = 0; r < 4; ++r) {
            x[r] = (c < 10) ? (acc[r] + bias) : -INFINITY;
            m[r] = x[r];
        }
        #pragma unroll
        for (int d = 1; d <= 8; d <<= 1)
            #pragma unroll
            for (int r = 0; r < 4; ++r) m[r] = fmaxf(m[r], __shfl_xor(m[r], d));
        #pragma unroll
        for (int r = 0; r < 4; ++r) { e[r] = (c < 10) ? expf(x[r] - m[r]) : 0.f; sm[r] = e[r]; }
        #pragma unroll
        for (int d = 1; d <= 8; d <<= 1)
            #pragma unroll
            for (int r = 0; r < 4; ++r) sm[r] += __shfl_xor(sm[r], d);
        if (c < 10 && h == wav) {
            #pragma unroll
            for (int r = 0; r < 4; ++r)
                pgf[(4 * wav + r) * 12 + c] = e[r] / sm[r];
        }

        // ---- digit-sum convolutions for be = wav ----
        if (lane < 38) {
            const int isH = (lane < 19), b = isH ? lane : lane - 19;
            const float* pg = pgf + 4 * wav * 12;
            const float* PA = pg + (isH ? 0 : 12);    // digit 0 / 1
            const float* PB = pg + (isH ? 24 : 36);   // digit 2 / 3
            const int ilo = (b > 9) ? b - 9 : 0;
            const int ihi = (b < 9) ? b : 9;
            float s = 0.f;
            for (int i = ilo; i <= ihi; ++i) s += PA[i] * PB[b - i];
            (isH ? Hf : Lf)[wav * 20 + b] = s;
        }

        // ---- outputs for be = wav: P_sum(s) = sum H[b]*L[s-10b] (<=2 terms) ----
        const float* H = Hf + wav * 20;
        const float* L = Lf + wav * 20;
        for (int s = lane; s < SUMS; s += 64) {
            const int bmin = (s > 18) ? (s - 9) / 10 : 0;
            int bmax = s / 10; if (bmax > 18) bmax = 18;
            float sum = 0.f;
            for (int b = bmin; b <= bmax; ++b) sum += H[b] * L[s - 10 * b];
            out[((size_t)bid * 2 + wav) * SUMS + s] = logf(sum);
        }
    }
}

extern "C" void kernel_launch(void* const* d_in, const int* in_sizes, int n_in,
                              void* d_out, int out_size, void* d_ws, size_t ws_size,
                              hipStream_t stream) {
    const float* images = (const float*)d_in[0];
    const float* c1w = (const float*)d_in[1];
    const float* c1b = (const float*)d_in[2];
    const float* c2w = (const float*)d_in[3];
    const float* c2b = (const float*)d_in[4];
    const float* f1w = (const float*)d_in[5];
    const float* f1b = (const float*)d_in[6];
    const float* f2w = (const float*)d_in[7];
    const float* f2b = (const float*)d_in[8];
    const float* f3w = (const float*)d_in[9];
    const float* f3b = (const float*)d_in[10];
    float* out = (float*)d_out;

    convert_weights<<<25, 256, 0, stream>>>(f1w, f2w, f3w, c1w, c2w, (uint4*)d_ws);
    lenet_circuit_kernel<<<NBLK, 256, 0, stream>>>(
        images, c1b, c2b, f1b, f2b, f3b, (const uint4*)d_ws, out);
}

// Round 5
// 134.358 us; speedup vs baseline: 1.1746x; 1.1746x over previous
//
#include <hip/hip_runtime.h>
#include <hip/hip_bf16.h>
#include <math.h>

#define SUMS 199
#define NBLK 2048   // 8 images = 2 batch elements per block, 256 threads

typedef __attribute__((ext_vector_type(8))) short short8;   // 8 bf16
typedef __attribute__((ext_vector_type(4))) float float4v;  // MFMA acc

union Frag8 { short8 v; unsigned u[4]; uint4 q; };

static __device__ inline unsigned pk_bf16(float a, float b) {
    __hip_bfloat162 h = __float22bfloat162_rn(make_float2(a, b));
    union { __hip_bfloat162 h; unsigned u; } c; c.h = h; return c.u;
}

// ---- pre-kernel: all weight fragments -> d_ws (bf16 frag layout) ----
// c2 K-map (dense): pos = 4*s + h, ky = pos/5, kx = pos%5, valid pos < 25
// => conv2 needs only 7 K-steps (K=224) instead of 8 (K=256).
__global__ __launch_bounds__(256) void convert_weights(
    const float* __restrict__ f1w, const float* __restrict__ f2w,
    const float* __restrict__ f3w, const float* __restrict__ c1w,
    const float* __restrict__ c2w, uint4* __restrict__ ws)
{
    const int g = blockIdx.x * 256 + threadIdx.x;
    if (g >= 6400) return;
    float v[8];
    if (g < 5824) {
        const float* W; int O, K, ld, nt, s, l;
        if (g < 4096)      { W = f1w; O = 120; K = 256; ld = 256; nt = g >> 9; s = (g >> 6) & 7; l = g & 63; }
        else if (g < 5632) { const int f = g - 4096; W = f2w; O = 84; K = 120; ld = 120; nt = f >> 8; s = (f >> 6) & 3; l = f & 63; }
        else               { const int f = g - 5632; W = f3w; O = 10; K = 84;  ld = 84;  nt = 0; s = f >> 6; l = f & 63; }
        const int o = nt * 16 + (l & 15);
        #pragma unroll
        for (int j = 0; j < 8; ++j) {
            const int k = 32 * s + 8 * (l >> 4) + j;
            v[j] = (o < O && k < K) ? W[o * ld + k] : 0.f;
        }
    } else if (g < 6336) {
        const int f = g - 5824, s = f >> 6, l = f & 63;
        const int c = l & 15, h = l >> 4;
        const int pos = 4 * s + h;           // dense position index
        const int ky = pos / 5, kx = pos % 5;
        const bool ok = (pos < 25);
        #pragma unroll
        for (int jp = 0; jp < 4; ++jp) {
            v[2 * jp]     = (ok && 2 * jp < 6)     ? c2w[c * 150 + (2 * jp) * 25 + ky * 5 + kx]     : 0.f;
            v[2 * jp + 1] = (ok && 2 * jp + 1 < 6) ? c2w[c * 150 + (2 * jp + 1) * 25 + ky * 5 + kx] : 0.f;
        }
    } else {
        const int l = (g - 6336) & 63;
        const int c = l & 15, h = l >> 4;
        const int oc = c >> 1, xs = c & 1;
        #pragma unroll
        for (int j = 0; j < 8; ++j) {
            const int p = h * 4 + (j >> 1);
            float w = 0.f;
            if (p < 15 && c < 12) {
                const int ky = p / 3, kx = 2 * (p % 3) + (j & 1) - xs;
                if (kx >= 0 && kx < 5) w = c1w[oc * 25 + ky * 5 + kx];
            }
            v[j] = w;
        }
    }
    uint4 r;
    r.x = pk_bf16(v[0], v[1]); r.y = pk_bf16(v[2], v[3]);
    r.z = pk_bf16(v[4], v[5]); r.w = pk_bf16(v[6], v[7]);
    ws[g] = r;
}

// LDS map, 19840 B (8 blocks/CU possible by LDS; actual residency set by
// VGPR allocation at __launch_bounds__(256,4) -> no spill; R4's (256,8)
// forced a 64-reg budget and spilled ~84 MB to scratch, -50%):
//  [0,6336)       imgu bf16 [4 wave-slots][396 dw] (1 image/slot/pass).
//                 After convs: A2 [8][68dw]@0, A3 [8][52dw]@2560,
//                 pgf [8][12]f32 @4352, Hf/Lf [2][20]f32 @4736/@4896.
//  [6336,15616)   p1 bf16 [4 wave-slots][145 uint4], ch-6/7 dwords stay 0.
//  [15616,19840)  A1 bf16 [8 img][132 dw]
//
// Front is fully wave-private: wave w stages image (pass*4+w), runs conv1
// (N-cols = (qyo,par,qxo): one image fills 16 cols; pool-y via shfl^4;
// stores hit banks 16qyo+4qxo+h, all distinct -> conflict-free), then conv2
// from its own p1 slot. No barriers until A1 is complete.
// fc1/fc2/fc3 duplicate image rows via (c&7) so all LDS reads stay in the
// 8-row regions (garbage rows are MFMA-row-isolated, outputs discarded).
// Circuit factorization (exact regroup): n1+n2 = 10(h1+h2)+(l1+l2) =>
// P_sum = (ptens1 (*) ptens2) outer-convolved with (pones1 (*) pones2);
// H,L are 19-long convs; each of the 199 outputs needs <=2 H[b]*L[a] terms.
// Tail runs on waves 0,1 (one batch element each), barrier-free.
__global__ __launch_bounds__(256, 4) void lenet_circuit_kernel(
    const float* __restrict__ images,
    const float* __restrict__ c1b, const float* __restrict__ c2b,
    const float* __restrict__ f1b, const float* __restrict__ f2b,
    const float* __restrict__ f3b, const uint4* __restrict__ wsb,
    float* __restrict__ out)
{
    __shared__ __align__(16) unsigned char s_mem[19840];
    unsigned*       imgu = (unsigned*)s_mem;
    uint2*          imgw = (uint2*)s_mem;
    unsigned short* p1s  = (unsigned short*)(s_mem + 6336);
    const uint4*    p1u4 = (const uint4*)(s_mem + 6336);
    unsigned*       A1d  = (unsigned*)(s_mem + 15616);
    const uint4*    A1q  = (const uint4*)(s_mem + 15616);
    float*          pgf  = (float*)(s_mem + 4352);    // [8][12] probs
    float*          Hf   = (float*)(s_mem + 4736);    // [2][20]
    float*          Lf   = (float*)(s_mem + 4896);    // [2][20]

    const int t = threadIdx.x, bid = blockIdx.x;
    const int lane = t & 63, wav = t >> 6;   // 4 waves
    const int c = lane & 15, h = lane >> 4;
    const uint4 z4 = {0u, 0u, 0u, 0u};

    // conv1 column decomposition: c = (qyo<<3) | (par<<2) | qxo
    const int qxo = c & 3, par = (c >> 2) & 1, qyo = c >> 3;

    // ---- zero own p1 slot (wave-private; pad ch 6-7 must stay 0) ----
    {
        uint4* pz = (uint4*)(s_mem + 6336) + wav * 145;
        for (int j = lane; j < 145; j += 64) pz[j] = z4;
    }
    // ---- load weight fragments (coalesced) ----
    Frag8 a1; a1.q = wsb[6336 + lane];
    int koff[7];
    #pragma unroll
    for (int s = 0; s < 7; ++s) {
        const int pos = 4 * s + h;
        koff[s] = (pos < 25) ? (pos / 5) * 12 + (pos % 5) : 0;
    }
    int pd[4];
    #pragma unroll
    for (int q = 0; q < 4; ++q) {
        const int p = 4 * h + q;
        pd[q] = (p < 15) ? (p / 3) * 14 + (p % 3) : 0;
    }
    float bias0 = 0.f, bias1 = 0.f;
    if (h < 3) { bias0 = c1b[2 * h]; bias1 = c1b[2 * h + 1]; }
    const float b2v = c2b[c];

    // ================= two passes, fully wave-private =================
    for (int pass = 0; pass < 2; ++pass) {
        // ---- stage own image fp32 -> bf16 into own imgu slot ----
        {
            const float4* g = (const float4*)(images) +
                              ((size_t)bid * 8 + pass * 4 + wav) * 196;
            #pragma unroll
            for (int k = 0; k < 4; ++k) {
                const int i = lane + 64 * k;
                if (i < 196) {
                    const float4 v = g[i];
                    uint2 wv; wv.x = pk_bf16(v.x, v.y); wv.y = pk_bf16(v.z, v.w);
                    imgw[wav * 198 + i] = wv;
                }
            }
        }
        // ---- conv1: 18 MFMA over own image ----
        {
            const int sbase = wav * 396 + (2 * qyo + par) * 14 + qxo;
            for (int Q = 0; Q < 6; ++Q) {
                #pragma unroll
                for (int qxg = 0; qxg < 3; ++qxg) {
                    const int base = sbase + Q * 56 + qxg * 4;
                    Frag8 bf;
                    #pragma unroll
                    for (int q = 0; q < 4; ++q) bf.u[q] = imgu[base + pd[q]];
                    float4v acc = {0.f, 0.f, 0.f, 0.f};
                    acc = __builtin_amdgcn_mfma_f32_16x16x32_bf16(a1.v, bf.v, acc, 0, 0, 0);
                    float v0 = fmaxf(acc[0], acc[1]);   // ch 2h, xs-pooled
                    float v1 = fmaxf(acc[2], acc[3]);   // ch 2h+1
                    v0 = fmaxf(v0, __shfl_xor(v0, 4));  // y-parity pool: lane bit 2
                    v1 = fmaxf(v1, __shfl_xor(v1, 4));
                    if (par == 0 && h < 3) {
                        const int qy = 2 * Q + qyo, qx = qxg * 4 + qxo;
                        *(unsigned*)&p1s[wav * 1160 + qy * 96 + qx * 8 + 2 * h] =
                            pk_bf16(fmaxf(v0 + bias0, 0.f), fmaxf(v1 + bias1, 0.f));
                    }
                }
            }
        }
        // ---- conv2: 28 MFMA over own p1 slot; writes A1 row (pass*4+wav) ----
        {
            const int pxl = (c & 1) + 2 * ((c >> 2) & 1);
            const int pyl = ((c >> 1) & 1) + 2 * ((c >> 3) & 1);
            int pbase[4];
            #pragma unroll
            for (int mt = 0; mt < 4; ++mt)
                pbase[mt] = wav * 145 + (pyl + 4 * (mt >> 1)) * 12 + pxl + 4 * (mt & 1);
            float4v acc[4];
            #pragma unroll
            for (int mt = 0; mt < 4; ++mt) acc[mt] = (float4v){0.f, 0.f, 0.f, 0.f};
            #pragma unroll
            for (int s = 0; s < 7; ++s) {
                Frag8 wz; wz.q = wsb[5824 + s * 64 + lane];  // L1/L2-hot stream
                #pragma unroll
                for (int mt = 0; mt < 4; ++mt) {
                    Frag8 af; af.q = p1u4[pbase[mt] + koff[s]];
                    acc[mt] = __builtin_amdgcn_mfma_f32_16x16x32_bf16(af.v, wz.v, acc[mt], 0, 0, 0);
                }
            }
            const int img = pass * 4 + wav;
            #pragma unroll
            for (int mt = 0; mt < 4; ++mt) {
                const float p = fmaxf(fmaxf(acc[mt][0], acc[mt][1]),
                                      fmaxf(acc[mt][2], acc[mt][3]));
                float v = fmaxf(p + b2v, 0.f);
                const float vp = __shfl_xor(v, 16);
                if ((h & 1) == 0) {
                    const int qy = (h >> 1) + 2 * (mt >> 1);
                    A1d[img * 132 + c * 8 + qy * 2 + (mt & 1)] = pk_bf16(v, vp);
                }
            }
        }
    }
    __syncthreads();     // A1 complete (8 images); imgu/p1 dead

    // ---- fc1 via MFMA (2 n-tiles/wave, 16 MFMA); image rows via (c&7) ----
    {
        unsigned* A2d = (unsigned*)s_mem;
        if (t < 32) A2d[(t >> 2) * 68 + 60 + (t & 3)] = 0u;   // k-pad 120-127
        float4v acc0 = {0.f, 0.f, 0.f, 0.f}, acc1 = acc0;
        const int nt0 = 2 * wav;
        #pragma unroll
        for (int s = 0; s < 8; ++s) {
            Frag8 af; af.q = A1q[(c & 7) * 33 + 4 * s + h];
            Frag8 b0; b0.q = wsb[(nt0 * 8 + s) * 64 + lane];
            Frag8 b1; b1.q = wsb[((nt0 + 1) * 8 + s) * 64 + lane];
            acc0 = __builtin_amdgcn_mfma_f32_16x16x32_bf16(af.v, b0.v, acc0, 0, 0, 0);
            acc1 = __builtin_amdgcn_mfma_f32_16x16x32_bf16(af.v, b1.v, acc1, 0, 0, 0);
        }
        #pragma unroll
        for (int ntl = 0; ntl < 2; ++ntl) {
            const int o = 32 * wav + 16 * ntl + c;
            const float bias = (o < 120) ? f1b[o] : 0.f;
            #pragma unroll
            for (int r = 0; r < 4; ++r) {
                float v = fmaxf((ntl ? acc1[r] : acc0[r]) + bias, 0.f);
                const float vp = __shfl_xor(v, 1);
                if ((c & 1) == 0 && o < 120 && h < 2)
                    A2d[(4 * h + r) * 68 + (o >> 1)] = pk_bf16(v, vp);
            }
        }
    }
    __syncthreads();

    // ---- fc2 via MFMA (waves 0-2, 2 n-tiles each) ----
    {
        unsigned* A3d = (unsigned*)(s_mem + 2560);
        if (t < 48) A3d[(t / 6) * 52 + 42 + (t % 6)] = 0u;    // k-pad 84-95
        if (wav < 3) {
            const uint4* A2q = (const uint4*)s_mem;
            float4v acc0 = {0.f, 0.f, 0.f, 0.f}, acc1 = acc0;
            const int nt0 = 2 * wav;
            #pragma unroll
            for (int s = 0; s < 4; ++s) {
                Frag8 af; af.q = A2q[(c & 7) * 17 + 4 * s + h];
                Frag8 b0; b0.q = wsb[4096 + (nt0 * 4 + s) * 64 + lane];
                Frag8 b1; b1.q = wsb[4096 + ((nt0 + 1) * 4 + s) * 64 + lane];
                acc0 = __builtin_amdgcn_mfma_f32_16x16x32_bf16(af.v, b0.v, acc0, 0, 0, 0);
                acc1 = __builtin_amdgcn_mfma_f32_16x16x32_bf16(af.v, b1.v, acc1, 0, 0, 0);
            }
            #pragma unroll
            for (int ntl = 0; ntl < 2; ++ntl) {
                const int o = 32 * wav + 16 * ntl + c;
                const float bias = (o < 84) ? f2b[o] : 0.f;
                #pragma unroll
                for (int r = 0; r < 4; ++r) {
                    float v = fmaxf((ntl ? acc1[r] : acc0[r]) + bias, 0.f);
                    const float vp = __shfl_xor(v, 1);
                    if ((c & 1) == 0 && o < 84 && h < 2)
                        A3d[(4 * h + r) * 52 + (o >> 1)] = pk_bf16(v, vp);
                }
            }
        }
    }
    __syncthreads();

    // ==== per-wave tail: waves 0,1 each own one batch element (be = wav).
    // fc3 rows m = 4h+r: wave w keeps h == w (its be's 4 digit images).
    // All LDS writes row-disjoint across the 2 waves; no barriers.
    if (wav < 2) {
        const uint4* A3q = (const uint4*)(s_mem + 2560);
        float4v acc = {0.f, 0.f, 0.f, 0.f};
        #pragma unroll
        for (int s = 0; s < 3; ++s) {
            Frag8 af; af.q = A3q[(c & 7) * 13 + 4 * s + h];
            Frag8 b; b.q = wsb[5632 + s * 64 + lane];
            acc = __builtin_amdgcn_mfma_f32_16x16x32_bf16(af.v, b.v, acc, 0, 0, 0);
        }
        const float bias = (c < 10) ? f3b[c] : 0.f;
        float x[4], m[4], e[4], sm[4];
        #pragma unroll
        for (int r = 0; r < 4; ++r) {
            x[r] = (c < 10) ? (acc[r] + bias) : -INFINITY;
            m[r] = x[r];
        }
        #pragma unroll
        for (int d = 1; d <= 8; d <<= 1)
            #pragma unroll
            for (int r = 0; r < 4; ++r) m[r] = fmaxf(m[r], __shfl_xor(m[r], d));
        #pragma unroll
        for (int r = 0; r < 4; ++r) { e[r] = (c < 10) ? expf(x[r] - m[r]) : 0.f; sm[r] = e[r]; }
        #pragma unroll
        for (int d = 1; d <= 8; d <<= 1)
            #pragma unroll
            for (int r = 0; r < 4; ++r) sm[r] += __shfl_xor(sm[r], d);
        if (c < 10 && h == wav) {
            #pragma unroll
            for (int r = 0; r < 4; ++r)
                pgf[(4 * wav + r) * 12 + c] = e[r] / sm[r];
        }

        // ---- digit-sum convolutions for be = wav ----
        if (lane < 38) {
            const int isH = (lane < 19), b = isH ? lane : lane - 19;
            const float* pg = pgf + 4 * wav * 12;
            const float* PA = pg + (isH ? 0 : 12);    // digit 0 / 1
            const float* PB = pg + (isH ? 24 : 36);   // digit 2 / 3
            const int ilo = (b > 9) ? b - 9 : 0;
            const int ihi = (b < 9) ? b : 9;
            float s = 0.f;
            for (int i = ilo; i <= ihi; ++i) s += PA[i] * PB[b - i];
            (isH ? Hf : Lf)[wav * 20 + b] = s;
        }

        // ---- outputs for be = wav: P_sum(s) = sum H[b]*L[s-10b] (<=2 terms) ----
        const float* H = Hf + wav * 20;
        const float* L = Lf + wav * 20;
        for (int s = lane; s < SUMS; s += 64) {
            const int bmin = (s > 18) ? (s - 9) / 10 : 0;
            int bmax = s / 10; if (bmax > 18) bmax = 18;
            float sum = 0.f;
            for (int b = bmin; b <= bmax; ++b) sum += H[b] * L[s - 10 * b];
            out[((size_t)bid * 2 + wav) * SUMS + s] = logf(sum);
        }
    }
}

extern "C" void kernel_launch(void* const* d_in, const int* in_sizes, int n_in,
                              void* d_out, int out_size, void* d_ws, size_t ws_size,
                              hipStream_t stream) {
    const float* images = (const float*)d_in[0];
    const float* c1w = (const float*)d_in[1];
    const float* c1b = (const float*)d_in[2];
    const float* c2w = (const float*)d_in[3];
    const float* c2b = (const float*)d_in[4];
    const float* f1w = (const float*)d_in[5];
    const float* f1b = (const float*)d_in[6];
    const float* f2w = (const float*)d_in[7];
    const float* f2b = (const float*)d_in[8];
    const float* f3w = (const float*)d_in[9];
    const float* f3b = (const float*)d_in[10];
    float* out = (float*)d_out;

    convert_weights<<<25, 256, 0, stream>>>(f1w, f2w, f3w, c1w, c2w, (uint4*)d_ws);
    lenet_circuit_kernel<<<NBLK, 256, 0, stream>>>(
        images, c1b, c2b, f1b, f2b, f3b, (const uint4*)d_ws, out);
}